// Round 1
// baseline (1904.992 us; speedup 1.0000x reference)
//
#include <hip/hip_runtime.h>
#include <math.h>

// Problem constants
#define S_LEN 2048
#define DMODEL 1024
#define NHEADS 16
#define HDIM 64
#define LATENT 256
#define NWHEELS 4
#define WOUT 256

// ---------------------------------------------------------------------------
// Generic tiled fp32 GEMM: C[M,N] = A[M,K] @ B[K,N] (+ bias[N] if non-null)
// 64x64 C-tile per block, 256 threads, 4x4 micro-tile per thread, KT=16.
// Requires M%64==0, N%64==0, K%16==0 (true for all shapes here).
// ---------------------------------------------------------------------------
#define TILE 64
#define KT 16

__global__ __launch_bounds__(256) void gemm_kernel(
    const float* __restrict__ A, int lda,
    const float* __restrict__ B, int ldb,
    float* __restrict__ C, int ldc,
    int M, int N, int K,
    const float* __restrict__ bias)
{
    __shared__ float As[KT][TILE + 1];  // [kk][row], +1 pad to break write conflicts
    __shared__ float Bs[KT][TILE];      // [kk][col], float4-aligned rows

    const int tid = threadIdx.x;
    const int tx = tid & 15;       // 0..15 -> col group
    const int ty = tid >> 4;       // 0..15 -> row group
    const int row0 = blockIdx.y * TILE;
    const int col0 = blockIdx.x * TILE;

    // A-load mapping: each thread loads float4 of A
    const int ar = tid >> 2;            // 0..63 tile row
    const int ak = (tid & 3) * 4;       // 0,4,8,12 within K-tile

    float acc[4][4];
#pragma unroll
    for (int i = 0; i < 4; i++)
#pragma unroll
        for (int j = 0; j < 4; j++) acc[i][j] = 0.0f;

    const int nkt = K / KT;
    for (int kt = 0; kt < nkt; kt++) {
        const int k0 = kt * KT;
        // Load A tile (64 rows x 16 k), transposed into As[kk][row]
        float4 av = *(const float4*)(A + (size_t)(row0 + ar) * lda + k0 + ak);
        As[ak + 0][ar] = av.x;
        As[ak + 1][ar] = av.y;
        As[ak + 2][ar] = av.z;
        As[ak + 3][ar] = av.w;
        // Load B tile (16 k x 64 cols), coalesced float4
        float4 bv = *(const float4*)(B + (size_t)(k0 + ty) * ldb + col0 + tx * 4);
        *(float4*)&Bs[ty][tx * 4] = bv;
        __syncthreads();

#pragma unroll
        for (int kk = 0; kk < KT; kk++) {
            float a0 = As[kk][ty * 4 + 0];
            float a1 = As[kk][ty * 4 + 1];
            float a2 = As[kk][ty * 4 + 2];
            float a3 = As[kk][ty * 4 + 3];
            float b0 = Bs[kk][tx * 4 + 0];
            float b1 = Bs[kk][tx * 4 + 1];
            float b2 = Bs[kk][tx * 4 + 2];
            float b3 = Bs[kk][tx * 4 + 3];
            acc[0][0] += a0 * b0; acc[0][1] += a0 * b1; acc[0][2] += a0 * b2; acc[0][3] += a0 * b3;
            acc[1][0] += a1 * b0; acc[1][1] += a1 * b1; acc[1][2] += a1 * b2; acc[1][3] += a1 * b3;
            acc[2][0] += a2 * b0; acc[2][1] += a2 * b1; acc[2][2] += a2 * b2; acc[2][3] += a2 * b3;
            acc[3][0] += a3 * b0; acc[3][1] += a3 * b1; acc[3][2] += a3 * b2; acc[3][3] += a3 * b3;
        }
        __syncthreads();
    }

    // Epilogue
#pragma unroll
    for (int i = 0; i < 4; i++) {
        float* cp = C + (size_t)(row0 + ty * 4 + i) * ldc + col0 + tx * 4;
        if (bias) {
            const float* bp = bias + col0 + tx * 4;
#pragma unroll
            for (int j = 0; j < 4; j++) cp[j] = acc[i][j] + bp[j];
        } else {
#pragma unroll
            for (int j = 0; j < 4; j++) cp[j] = acc[i][j];
        }
    }
}

// ---------------------------------------------------------------------------
// Flash-style attention for one head / 32-row Q-block per workgroup.
// q,k,v: [S, NHEADS*HDIM] fp32; ctx: [S, NHEADS*HDIM] fp32.
// 256 threads: thread t owns (row = t>>3, dims (t&7)*8 .. +8) of the O tile.
// ---------------------------------------------------------------------------
#define QT 32
#define KTL 32

__global__ __launch_bounds__(256) void attn_kernel(
    const float* __restrict__ q,
    const float* __restrict__ k,
    const float* __restrict__ v,
    float* __restrict__ ctx)
{
    __shared__ float Qs[QT][HDIM];
    __shared__ float Ks[KTL][HDIM];
    __shared__ float Vs[KTL][HDIM];
    __shared__ float Ps[QT][KTL];
    __shared__ float mrow[QT], lrow[QT], arow[QT];

    const int h = blockIdx.y;
    const int qb = blockIdx.x;
    const int tid = threadIdx.x;
    const int r = tid >> 3;            // 0..31 (row in tile)
    const int d0 = (tid & 7) * 8;      // 0..56 (dim chunk)
    const float scale = 0.125f;        // 1/sqrt(64)

    // Load Q tile (rows qb*32..+32, cols h*64..+64)
    {
        const float* qp = q + (size_t)(qb * QT + r) * DMODEL + h * HDIM + d0;
        *(float4*)&Qs[r][d0] = *(const float4*)qp;
        *(float4*)&Qs[r][d0 + 4] = *(const float4*)(qp + 4);
    }
    if (tid < QT) { mrow[tid] = -INFINITY; lrow[tid] = 0.0f; }

    float o[8];
#pragma unroll
    for (int i = 0; i < 8; i++) o[i] = 0.0f;

    const int ntiles = S_LEN / KTL;
    for (int kt = 0; kt < ntiles; kt++) {
        // Load K,V tiles
        {
            const size_t off = (size_t)(kt * KTL + r) * DMODEL + h * HDIM + d0;
            *(float4*)&Ks[r][d0]     = *(const float4*)(k + off);
            *(float4*)&Ks[r][d0 + 4] = *(const float4*)(k + off + 4);
            *(float4*)&Vs[r][d0]     = *(const float4*)(v + off);
            *(float4*)&Vs[r][d0 + 4] = *(const float4*)(v + off + 4);
        }
        __syncthreads();

        // Scores: thread computes 4 entries of S[32][32]: row r, cols sc0..sc0+3
        {
            const int sc0 = (tid & 7) * 4;
            float s0 = 0.f, s1 = 0.f, s2 = 0.f, s3 = 0.f;
#pragma unroll
            for (int d4 = 0; d4 < HDIM; d4 += 4) {
                float4 qv = *(const float4*)&Qs[r][d4];
                float4 k0v = *(const float4*)&Ks[sc0 + 0][d4];
                float4 k1v = *(const float4*)&Ks[sc0 + 1][d4];
                float4 k2v = *(const float4*)&Ks[sc0 + 2][d4];
                float4 k3v = *(const float4*)&Ks[sc0 + 3][d4];
                s0 += qv.x * k0v.x + qv.y * k0v.y + qv.z * k0v.z + qv.w * k0v.w;
                s1 += qv.x * k1v.x + qv.y * k1v.y + qv.z * k1v.z + qv.w * k1v.w;
                s2 += qv.x * k2v.x + qv.y * k2v.y + qv.z * k2v.z + qv.w * k2v.w;
                s3 += qv.x * k3v.x + qv.y * k3v.y + qv.z * k3v.z + qv.w * k3v.w;
            }
            Ps[r][sc0 + 0] = s0 * scale;
            Ps[r][sc0 + 1] = s1 * scale;
            Ps[r][sc0 + 2] = s2 * scale;
            Ps[r][sc0 + 3] = s3 * scale;
        }
        __syncthreads();

        // Online softmax row update (one thread per row)
        if (tid < QT) {
            float m_old = mrow[tid];
            float m_new = m_old;
#pragma unroll
            for (int j = 0; j < KTL; j++) m_new = fmaxf(m_new, Ps[tid][j]);
            float a = __expf(m_old - m_new);   // 0 on first tile (m_old=-inf)
            float sum = 0.0f;
#pragma unroll
            for (int j = 0; j < KTL; j++) {
                float p = __expf(Ps[tid][j] - m_new);
                Ps[tid][j] = p;
                sum += p;
            }
            mrow[tid] = m_new;
            lrow[tid] = lrow[tid] * a + sum;
            arow[tid] = a;
        }
        __syncthreads();

        // O update: o = o*alpha + P[r][:] @ V[:, d0..d0+8]
        {
            const float a = arow[r];
#pragma unroll
            for (int i = 0; i < 8; i++) o[i] *= a;
            for (int j = 0; j < KTL; j++) {
                float p = Ps[r][j];
                float4 v0 = *(const float4*)&Vs[j][d0];
                float4 v1 = *(const float4*)&Vs[j][d0 + 4];
                o[0] += p * v0.x; o[1] += p * v0.y; o[2] += p * v0.z; o[3] += p * v0.w;
                o[4] += p * v1.x; o[5] += p * v1.y; o[6] += p * v1.z; o[7] += p * v1.w;
            }
        }
        __syncthreads();
    }

    // Normalize and write ctx
    {
        const float inv_l = 1.0f / lrow[r];
        float* cp = ctx + (size_t)(qb * QT + r) * DMODEL + h * HDIM + d0;
        float4 o0 = make_float4(o[0] * inv_l, o[1] * inv_l, o[2] * inv_l, o[3] * inv_l);
        float4 o1 = make_float4(o[4] * inv_l, o[5] * inv_l, o[6] * inv_l, o[7] * inv_l);
        *(float4*)cp = o0;
        *(float4*)(cp + 4) = o1;
    }
}

// ---------------------------------------------------------------------------
// Launch
// ---------------------------------------------------------------------------
extern "C" void kernel_launch(void* const* d_in, const int* in_sizes, int n_in,
                              void* d_out, int out_size, void* d_ws, size_t ws_size,
                              hipStream_t stream) {
    const float* emb    = (const float*)d_in[0];  // [2048,1024]
    const float* Wq     = (const float*)d_in[1];  // [1024,1024]
    const float* Wdkv   = (const float*)d_in[2];  // [1024,256]
    const float* Wuk    = (const float*)d_in[3];  // [256,1024]
    const float* Wuv    = (const float*)d_in[4];  // [256,1024]
    const float* Wo     = (const float*)d_in[5];  // [1024,1024]
    const float* wheelW = (const float*)d_in[6];  // [4,1024,256]
    const float* wheelB = (const float*)d_in[7];  // [4,256]
    float* out = (float*)d_out;                   // [2048,2048]

    // Workspace layout (fp32 elements)
    float* ws   = (float*)d_ws;
    float* q_ws  = ws;                                   // 2048*1024
    float* ckv   = q_ws + (size_t)S_LEN * DMODEL;        // 2048*256
    float* k_ws  = ckv + (size_t)S_LEN * LATENT;         // 2048*1024
    float* v_ws  = k_ws + (size_t)S_LEN * DMODEL;        // 2048*1024
    float* ctx   = v_ws + (size_t)S_LEN * DMODEL;        // 2048*1024

    dim3 blk(256);

    // q = emb @ Wq            [2048,1024]
    gemm_kernel<<<dim3(DMODEL / TILE, S_LEN / TILE), blk, 0, stream>>>(
        emb, DMODEL, Wq, DMODEL, q_ws, DMODEL, S_LEN, DMODEL, DMODEL, nullptr);
    // c_kv = emb @ Wdkv       [2048,256]
    gemm_kernel<<<dim3(LATENT / TILE, S_LEN / TILE), blk, 0, stream>>>(
        emb, DMODEL, Wdkv, LATENT, ckv, LATENT, S_LEN, LATENT, DMODEL, nullptr);
    // k = c_kv @ Wuk          [2048,1024]
    gemm_kernel<<<dim3(DMODEL / TILE, S_LEN / TILE), blk, 0, stream>>>(
        ckv, LATENT, Wuk, DMODEL, k_ws, DMODEL, S_LEN, DMODEL, LATENT, nullptr);
    // v = c_kv @ Wuv          [2048,1024]
    gemm_kernel<<<dim3(DMODEL / TILE, S_LEN / TILE), blk, 0, stream>>>(
        ckv, LATENT, Wuv, DMODEL, v_ws, DMODEL, S_LEN, DMODEL, LATENT, nullptr);
    // attention -> ctx        [2048,1024]
    attn_kernel<<<dim3(S_LEN / QT, NHEADS), blk, 0, stream>>>(q_ws, k_ws, v_ws, ctx);
    // body = ctx @ Wo -> out[:, 0:1024]  (ldc = 2048)
    gemm_kernel<<<dim3(DMODEL / TILE, S_LEN / TILE), blk, 0, stream>>>(
        ctx, DMODEL, Wo, DMODEL, out, 2 * DMODEL, S_LEN, DMODEL, DMODEL, nullptr);
    // wheels: out[:, 1024 + w*256 .. ] = body @ wheel_W[w] + wheel_b[w]
    for (int w = 0; w < NWHEELS; w++) {
        gemm_kernel<<<dim3(WOUT / TILE, S_LEN / TILE), blk, 0, stream>>>(
            out, 2 * DMODEL,                       // A = body (cols 0..1023 of out)
            wheelW + (size_t)w * DMODEL * WOUT, WOUT,
            out + DMODEL + (size_t)w * WOUT, 2 * DMODEL,
            S_LEN, WOUT, DMODEL,
            wheelB + (size_t)w * WOUT);
    }
}

// Round 2
// 645.785 us; speedup vs baseline: 2.9499x; 2.9499x over previous
//
#include <hip/hip_runtime.h>
#include <math.h>

// Problem constants
#define S_LEN 2048
#define DMODEL 1024
#define NHEADS 16
#define HDIM 64
#define LATENT 256
#define NWHEELS 4
#define WOUT 256

typedef __bf16 bf16x8 __attribute__((ext_vector_type(8)));
typedef __bf16 bf16x4 __attribute__((ext_vector_type(4)));
typedef float  f32x4  __attribute__((ext_vector_type(4)));

// ---------------------------------------------------------------------------
// Generic tiled fp32 GEMM: C[M,N] = A[M,K] @ B[K,N] (+ bias[N] if non-null)
// 64x64 C-tile per block, 256 threads, 4x4 micro-tile per thread, KT=16.
// ---------------------------------------------------------------------------
#define TILE 64
#define KT 16

__global__ __launch_bounds__(256) void gemm_kernel(
    const float* __restrict__ A, int lda,
    const float* __restrict__ B, int ldb,
    float* __restrict__ C, int ldc,
    int M, int N, int K,
    const float* __restrict__ bias)
{
    __shared__ float As[KT][TILE + 1];
    __shared__ float Bs[KT][TILE];

    const int tid = threadIdx.x;
    const int tx = tid & 15;
    const int ty = tid >> 4;
    const int row0 = blockIdx.y * TILE;
    const int col0 = blockIdx.x * TILE;

    const int ar = tid >> 2;
    const int ak = (tid & 3) * 4;

    float acc[4][4];
#pragma unroll
    for (int i = 0; i < 4; i++)
#pragma unroll
        for (int j = 0; j < 4; j++) acc[i][j] = 0.0f;

    const int nkt = K / KT;
    for (int kt = 0; kt < nkt; kt++) {
        const int k0 = kt * KT;
        float4 av = *(const float4*)(A + (size_t)(row0 + ar) * lda + k0 + ak);
        As[ak + 0][ar] = av.x;
        As[ak + 1][ar] = av.y;
        As[ak + 2][ar] = av.z;
        As[ak + 3][ar] = av.w;
        float4 bv = *(const float4*)(B + (size_t)(k0 + ty) * ldb + col0 + tx * 4);
        *(float4*)&Bs[ty][tx * 4] = bv;
        __syncthreads();

#pragma unroll
        for (int kk = 0; kk < KT; kk++) {
            float a0 = As[kk][ty * 4 + 0];
            float a1 = As[kk][ty * 4 + 1];
            float a2 = As[kk][ty * 4 + 2];
            float a3 = As[kk][ty * 4 + 3];
            float b0 = Bs[kk][tx * 4 + 0];
            float b1 = Bs[kk][tx * 4 + 1];
            float b2 = Bs[kk][tx * 4 + 2];
            float b3 = Bs[kk][tx * 4 + 3];
            acc[0][0] += a0 * b0; acc[0][1] += a0 * b1; acc[0][2] += a0 * b2; acc[0][3] += a0 * b3;
            acc[1][0] += a1 * b0; acc[1][1] += a1 * b1; acc[1][2] += a1 * b2; acc[1][3] += a1 * b3;
            acc[2][0] += a2 * b0; acc[2][1] += a2 * b1; acc[2][2] += a2 * b2; acc[2][3] += a2 * b3;
            acc[3][0] += a3 * b0; acc[3][1] += a3 * b1; acc[3][2] += a3 * b2; acc[3][3] += a3 * b3;
        }
        __syncthreads();
    }

#pragma unroll
    for (int i = 0; i < 4; i++) {
        float* cp = C + (size_t)(row0 + ty * 4 + i) * ldc + col0 + tx * 4;
        if (bias) {
            const float* bp = bias + col0 + tx * 4;
#pragma unroll
            for (int j = 0; j < 4; j++) cp[j] = acc[i][j] + bp[j];
        } else {
#pragma unroll
            for (int j = 0; j < 4; j++) cp[j] = acc[i][j];
        }
    }
}

// ---------------------------------------------------------------------------
// MFMA flash attention.
// Block = 64 Q-rows x 1 head, 256 threads = 4 waves; wave w owns rows w*16..+16.
// K-tiles of 64 keys. QK^T and PV via mfma_f32_16x16x32_bf16.
//
// Layouts (verified per guide §3 for 16x16x32):
//   A[m][k]: m = lane&15, k = (lane>>4)*8 + j   (8 contiguous k per lane)
//   B[k][n]: n = lane&15, k = (lane>>4)*8 + j
//   C/D   : col = lane&15, row = (lane>>4)*4 + reg
//
// LDS: Ks [64 keys][72] bf16 (d-blocks XOR-swizzled by key>>3)
//      Vt [64 dims][72] bf16 (key-blocks XOR-swizzled by dim>>3)
//      Ps per-wave [16][72] bf16 (no swizzle; pitch-72 spreads banks)
// ---------------------------------------------------------------------------
#define PITCH 72

__global__ __launch_bounds__(256) void attn_mfma_kernel(
    const float* __restrict__ q,
    const float* __restrict__ k,
    const float* __restrict__ v,
    float* __restrict__ ctx)
{
    __shared__ __bf16 Ks[64 * PITCH];
    __shared__ __bf16 Vt[64 * PITCH];
    __shared__ __bf16 Ps[4 * 16 * PITCH];

    const int h  = blockIdx.y;
    const int qb = blockIdx.x;
    const int tid  = threadIdx.x;
    const int lane = tid & 63;
    const int w    = tid >> 6;        // wave 0..3
    const int quad = lane >> 4;       // 0..3
    const int c0   = lane & 15;       // 0..15
    const float scale = 0.125f;       // 1/sqrt(64)

    // ---- Load Q fragments (scaled, bf16), held for whole kernel ----
    bf16x8 qfrag[2];
    {
        const float* qrow = q + (size_t)(qb * 64 + w * 16 + c0) * DMODEL + h * HDIM;
#pragma unroll
        for (int ks = 0; ks < 2; ks++) {
            const float* p = qrow + ks * 32 + quad * 8;
            float4 f0 = *(const float4*)(p);
            float4 f1 = *(const float4*)(p + 4);
            bf16x8 f;
            f[0] = (__bf16)(f0.x * scale); f[1] = (__bf16)(f0.y * scale);
            f[2] = (__bf16)(f0.z * scale); f[3] = (__bf16)(f0.w * scale);
            f[4] = (__bf16)(f1.x * scale); f[5] = (__bf16)(f1.y * scale);
            f[6] = (__bf16)(f1.z * scale); f[7] = (__bf16)(f1.w * scale);
            qfrag[ks] = f;
        }
    }

    f32x4 Ofrag[4];
#pragma unroll
    for (int nb = 0; nb < 4; nb++) Ofrag[nb] = (f32x4){0.f, 0.f, 0.f, 0.f};
    float m_r[4] = {-INFINITY, -INFINITY, -INFINITY, -INFINITY};
    float l_r[4] = {0.f, 0.f, 0.f, 0.f};

    // Staging mapping: thread tid loads key row (tid>>2), dim quarter (tid&3)*16.
    const int skey = tid >> 2;
    const int sq   = (tid & 3) * 16;
    const int kswz = (skey >> 3) & 7;

    __bf16* Pw = Ps + w * (16 * PITCH);

    for (int kt = 0; kt < S_LEN / 64; kt++) {
        // ---- Stage K tile (row-major, swizzled) and V tile (transposed, swizzled) ----
        {
            const size_t roff = (size_t)(kt * 64 + skey) * DMODEL + h * HDIM + sq;
            const float* krow = k + roff;
            const float* vrow = v + roff;
#pragma unroll
            for (int c = 0; c < 16; c += 4) {
                const int d = sq + c;                    // 0..63, d&7 in {0,4}
                float4 kv = *(const float4*)(krow + c);
                bf16x4 kb;
                kb[0] = (__bf16)kv.x; kb[1] = (__bf16)kv.y;
                kb[2] = (__bf16)kv.z; kb[3] = (__bf16)kv.w;
                *(bf16x4*)&Ks[skey * PITCH + ((((d >> 3) ^ kswz) << 3) | (d & 7))] = kb;

                float4 vv = *(const float4*)(vrow + c);
                float vva[4] = {vv.x, vv.y, vv.z, vv.w};
#pragma unroll
                for (int e = 0; e < 4; e++) {
                    const int dd = d + e;
                    Vt[dd * PITCH + ((((skey >> 3) ^ ((dd >> 3) & 7)) << 3) | (skey & 7))] =
                        (__bf16)vva[e];
                }
            }
        }
        __syncthreads();

        // ---- Scores: S[16x64] per wave, 4 n-blocks x 2 k-steps ----
        f32x4 sfrag[4];
#pragma unroll
        for (int nb = 0; nb < 4; nb++) {
            f32x4 acc = (f32x4){0.f, 0.f, 0.f, 0.f};
            const int n = nb * 16 + c0;                  // key index
            const int nswz = (n >> 3) & 7;
#pragma unroll
            for (int ks = 0; ks < 2; ks++) {
                bf16x8 bfrag = *(const bf16x8*)&Ks[n * PITCH + (((ks * 4 + quad) ^ nswz) << 3)];
                acc = __builtin_amdgcn_mfma_f32_16x16x32_bf16(qfrag[ks], bfrag, acc, 0, 0, 0);
            }
            sfrag[nb] = acc;
        }

        // ---- Online softmax (row r = w*16 + quad*4 + reg spread over 16 lanes) ----
        float alpha_v[4];
#pragma unroll
        for (int reg = 0; reg < 4; reg++) {
            float mloc = fmaxf(fmaxf(sfrag[0][reg], sfrag[1][reg]),
                               fmaxf(sfrag[2][reg], sfrag[3][reg]));
#pragma unroll
            for (int mask = 1; mask < 16; mask <<= 1)
                mloc = fmaxf(mloc, __shfl_xor(mloc, mask, 64));
            const float mnew = fmaxf(m_r[reg], mloc);
            const float al = __expf(m_r[reg] - mnew);    // 0 on first tile
            m_r[reg] = mnew;
            float rsum = 0.f;
#pragma unroll
            for (int nb = 0; nb < 4; nb++) {
                float p = __expf(sfrag[nb][reg] - mnew);
                sfrag[nb][reg] = p;
                rsum += p;
            }
#pragma unroll
            for (int mask = 1; mask < 16; mask <<= 1)
                rsum += __shfl_xor(rsum, mask, 64);
            l_r[reg] = l_r[reg] * al + rsum;
            alpha_v[reg] = al;
        }

        // ---- P: C-layout -> LDS -> A-layout (per-wave strip, no x-wave barrier) ----
#pragma unroll
        for (int reg = 0; reg < 4; reg++) {
            const int prow = quad * 4 + reg;
#pragma unroll
            for (int nb = 0; nb < 4; nb++)
                Pw[prow * PITCH + nb * 16 + c0] = (__bf16)sfrag[nb][reg];
        }
        __asm__ __volatile__("s_waitcnt lgkmcnt(0)" ::: "memory");

        bf16x8 pfrag[2];
#pragma unroll
        for (int ks = 0; ks < 2; ks++)
            pfrag[ks] = *(const bf16x8*)&Pw[c0 * PITCH + ks * 32 + quad * 8];

        // ---- O = O*alpha + P @ V ----
        const f32x4 av = {alpha_v[0], alpha_v[1], alpha_v[2], alpha_v[3]};
#pragma unroll
        for (int nb = 0; nb < 4; nb++) {
            f32x4 acc = Ofrag[nb] * av;
            const int n = nb * 16 + c0;                  // dim index
            const int nswz = (n >> 3) & 7;
#pragma unroll
            for (int ks = 0; ks < 2; ks++) {
                bf16x8 vf = *(const bf16x8*)&Vt[n * PITCH + (((ks * 4 + quad) ^ nswz) << 3)];
                acc = __builtin_amdgcn_mfma_f32_16x16x32_bf16(pfrag[ks], vf, acc, 0, 0, 0);
            }
            Ofrag[nb] = acc;
        }
        __syncthreads();
    }

    // ---- Epilogue: normalize, write ctx ----
    float inv_l[4];
#pragma unroll
    for (int reg = 0; reg < 4; reg++) inv_l[reg] = 1.0f / l_r[reg];
    const int orow0 = qb * 64 + w * 16 + quad * 4;
#pragma unroll
    for (int reg = 0; reg < 4; reg++) {
        float* cp = ctx + (size_t)(orow0 + reg) * DMODEL + h * HDIM + c0;
#pragma unroll
        for (int nb = 0; nb < 4; nb++)
            cp[nb * 16] = Ofrag[nb][reg] * inv_l[reg];
    }
}

// ---------------------------------------------------------------------------
// Launch
// ---------------------------------------------------------------------------
extern "C" void kernel_launch(void* const* d_in, const int* in_sizes, int n_in,
                              void* d_out, int out_size, void* d_ws, size_t ws_size,
                              hipStream_t stream) {
    const float* emb    = (const float*)d_in[0];  // [2048,1024]
    const float* Wq     = (const float*)d_in[1];  // [1024,1024]
    const float* Wdkv   = (const float*)d_in[2];  // [1024,256]
    const float* Wuk    = (const float*)d_in[3];  // [256,1024]
    const float* Wuv    = (const float*)d_in[4];  // [256,1024]
    const float* Wo     = (const float*)d_in[5];  // [1024,1024]
    const float* wheelW = (const float*)d_in[6];  // [4,1024,256]
    const float* wheelB = (const float*)d_in[7];  // [4,256]
    float* out = (float*)d_out;                   // [2048,2048]

    float* ws   = (float*)d_ws;
    float* q_ws  = ws;                                   // 2048*1024
    float* ckv   = q_ws + (size_t)S_LEN * DMODEL;        // 2048*256
    float* k_ws  = ckv + (size_t)S_LEN * LATENT;         // 2048*1024
    float* v_ws  = k_ws + (size_t)S_LEN * DMODEL;        // 2048*1024
    float* ctx   = v_ws + (size_t)S_LEN * DMODEL;        // 2048*1024

    dim3 blk(256);

    gemm_kernel<<<dim3(DMODEL / TILE, S_LEN / TILE), blk, 0, stream>>>(
        emb, DMODEL, Wq, DMODEL, q_ws, DMODEL, S_LEN, DMODEL, DMODEL, nullptr);
    gemm_kernel<<<dim3(LATENT / TILE, S_LEN / TILE), blk, 0, stream>>>(
        emb, DMODEL, Wdkv, LATENT, ckv, LATENT, S_LEN, LATENT, DMODEL, nullptr);
    gemm_kernel<<<dim3(DMODEL / TILE, S_LEN / TILE), blk, 0, stream>>>(
        ckv, LATENT, Wuk, DMODEL, k_ws, DMODEL, S_LEN, DMODEL, LATENT, nullptr);
    gemm_kernel<<<dim3(DMODEL / TILE, S_LEN / TILE), blk, 0, stream>>>(
        ckv, LATENT, Wuv, DMODEL, v_ws, DMODEL, S_LEN, DMODEL, LATENT, nullptr);

    attn_mfma_kernel<<<dim3(S_LEN / 64, NHEADS), blk, 0, stream>>>(q_ws, k_ws, v_ws, ctx);

    gemm_kernel<<<dim3(DMODEL / TILE, S_LEN / TILE), blk, 0, stream>>>(
        ctx, DMODEL, Wo, DMODEL, out, 2 * DMODEL, S_LEN, DMODEL, DMODEL, nullptr);
    for (int wgem = 0; wgem < NWHEELS; wgem++) {
        gemm_kernel<<<dim3(WOUT / TILE, S_LEN / TILE), blk, 0, stream>>>(
            out, 2 * DMODEL,
            wheelW + (size_t)wgem * DMODEL * WOUT, WOUT,
            out + DMODEL + (size_t)wgem * WOUT, 2 * DMODEL,
            S_LEN, WOUT, DMODEL,
            wheelB + (size_t)wgem * WOUT);
    }
}

// Round 3
// 362.807 us; speedup vs baseline: 5.2507x; 1.7800x over previous
//
#include <hip/hip_runtime.h>
#include <math.h>

#define S_LEN 2048
#define DMODEL 1024
#define NHEADS 16
#define HDIM 64
#define LATENT 256

typedef __bf16 bf16x8 __attribute__((ext_vector_type(8)));
typedef __bf16 bf16x4 __attribute__((ext_vector_type(4)));
typedef float  f32x4  __attribute__((ext_vector_type(4)));

// async global->LDS, 16B per lane. LDS dest = wave-uniform base + lane*16.
__device__ __forceinline__ void gld_lds16(void* lds, const void* g) {
    __builtin_amdgcn_global_load_lds(
        (__attribute__((address_space(1))) void*)(g),
        (__attribute__((address_space(3))) void*)(lds), 16, 0, 0);
}

// ---------------------------------------------------------------------------
// bf16 MFMA GEMM (m97 structure). C[M,N] = A[M,K] @ Bt[N,K]^T.
// 128x128 tile, BK=64, 256 thr = 4 waves, wave does 64x64 via 4x4 16x16x32.
// LDS rows = 64 bf16 = 128 B = 8 chunks of 16 B, XOR-swizzled: logical chunk c
// of row r stored at chunk c^(r&7)  (staging permutes the source k-offset).
// Epilogue: optional fp32 out (+bias), optional bf16 out:
//   bmode 0 plain [m][n]; 1 split hi|lo|hi at col offsets 0,soff,2*soff;
//   2 transposed [n][m].
// ---------------------------------------------------------------------------
__global__ __launch_bounds__(256) void gemm_bf16(
    const __bf16* __restrict__ A, int lda,
    const __bf16* __restrict__ Bt, int ldb,
    int M, int N, int K,
    float* __restrict__ Cf, int ldcf, const float* __restrict__ bias,
    __bf16* __restrict__ Cb, int ldcb, int bmode, int soff,
    float out_scale)
{
    __shared__ __bf16 sA[128 * 64];
    __shared__ __bf16 sB[128 * 64];

    const int tid  = threadIdx.x;
    const int lane = tid & 63;
    const int w    = tid >> 6;
    const int quad = lane >> 4;
    const int c0   = lane & 15;
    const int m0 = blockIdx.y * 128;
    const int n0 = blockIdx.x * 128;

    // staging source pointers (swizzled k-offset), advance by 64 per K-tile
    const int srow = lane >> 3;     // 0..7 within 8-row chunk
    const int sc   = lane & 7;      // stored chunk
    const __bf16* a_src[4]; const __bf16* b_src[4];
    __bf16* a_dst[4]; __bf16* b_dst[4];
#pragma unroll
    for (int t = 0; t < 4; t++) {
        const int row = w * 32 + t * 8 + srow;
        const int c = sc ^ (row & 7);
        a_src[t] = A  + (size_t)(m0 + row) * lda + c * 8;
        b_src[t] = Bt + (size_t)(n0 + row) * ldb + c * 8;
        a_dst[t] = &sA[(w * 32 + t * 8) * 64];
        b_dst[t] = &sB[(w * 32 + t * 8) * 64];
    }

    // fragment-read rows
    const int mw = (w & 1) * 64;
    const int nw = (w >> 1) * 64;
    int arow[4], brow[4];
#pragma unroll
    for (int i = 0; i < 4; i++) {
        arow[i] = mw + i * 16 + c0;
        brow[i] = nw + i * 16 + c0;
    }

    f32x4 acc[4][4];
#pragma unroll
    for (int i = 0; i < 4; i++)
#pragma unroll
        for (int j = 0; j < 4; j++) acc[i][j] = (f32x4){0.f, 0.f, 0.f, 0.f};

    const int nkt = K >> 6;
    for (int kt = 0; kt < nkt; kt++) {
#pragma unroll
        for (int t = 0; t < 4; t++) {
            gld_lds16(a_dst[t], a_src[t]); a_src[t] += 64;
            gld_lds16(b_dst[t], b_src[t]); b_src[t] += 64;
        }
        __syncthreads();

#pragma unroll
        for (int ks = 0; ks < 2; ks++) {
            const int cb = ks * 4 + quad;
            bf16x8 af[4], bf[4];
#pragma unroll
            for (int i = 0; i < 4; i++)
                af[i] = *(const bf16x8*)&sA[arow[i] * 64 + ((cb ^ (arow[i] & 7)) << 3)];
#pragma unroll
            for (int j = 0; j < 4; j++)
                bf[j] = *(const bf16x8*)&sB[brow[j] * 64 + ((cb ^ (brow[j] & 7)) << 3)];
#pragma unroll
            for (int i = 0; i < 4; i++)
#pragma unroll
                for (int j = 0; j < 4; j++)
                    acc[i][j] = __builtin_amdgcn_mfma_f32_16x16x32_bf16(af[i], bf[j], acc[i][j], 0, 0, 0);
        }
        __syncthreads();
    }

    // epilogue
    float bias_v[4];
    if (bias) {
#pragma unroll
        for (int j = 0; j < 4; j++) bias_v[j] = bias[n0 + nw + j * 16 + c0];
    }
#pragma unroll
    for (int i = 0; i < 4; i++) {
#pragma unroll
        for (int reg = 0; reg < 4; reg++) {
            const int m = m0 + mw + i * 16 + quad * 4 + reg;
#pragma unroll
            for (int j = 0; j < 4; j++) {
                const int n = n0 + nw + j * 16 + c0;
                float val = acc[i][j][reg] * out_scale;
                if (bias) val += bias_v[j];
                if (Cf) Cf[(size_t)m * ldcf + n] = val;
                if (Cb) {
                    if (bmode == 0) {
                        Cb[(size_t)m * ldcb + n] = (__bf16)val;
                    } else if (bmode == 1) {
                        __bf16 hi = (__bf16)val;
                        __bf16 lo = (__bf16)(val - (float)hi);
                        __bf16* p = Cb + (size_t)m * ldcb + n;
                        p[0] = hi; p[soff] = lo; p[2 * soff] = hi;
                    } else {
                        Cb[(size_t)n * ldcb + m] = (__bf16)val;
                    }
                }
            }
        }
    }
}

// ---------------------------------------------------------------------------
// MFMA flash attention, bf16 inputs. qs pre-scaled bf16 [S,1024]; kk bf16
// [S,1024]; vT bf16 [1024,S]. Output ctx2 bf16 [S,3072] hi|lo|hi split.
// Block = 64 Q x 1 head; K/Vt staged via global_load_lds (swizzled rows).
// ---------------------------------------------------------------------------
#define PITCH 72

__global__ __launch_bounds__(256) void attn_mfma_kernel(
    const __bf16* __restrict__ qs,
    const __bf16* __restrict__ kk,
    const __bf16* __restrict__ vT,
    __bf16* __restrict__ ctx2)
{
    __shared__ __bf16 Ks[64 * 64];
    __shared__ __bf16 Vt[64 * 64];
    __shared__ __bf16 Ps[4 * 16 * PITCH];

    const int h  = blockIdx.y;
    const int qb = blockIdx.x;
    const int tid  = threadIdx.x;
    const int lane = tid & 63;
    const int w    = tid >> 6;
    const int quad = lane >> 4;
    const int c0   = lane & 15;

    // Q fragments (already scaled by 1/8 in GEMM epilogue)
    bf16x8 qfrag[2];
    {
        const __bf16* qrow = qs + (size_t)(qb * 64 + w * 16 + c0) * DMODEL + h * HDIM;
        qfrag[0] = *(const bf16x8*)(qrow + quad * 8);
        qfrag[1] = *(const bf16x8*)(qrow + 32 + quad * 8);
    }

    // staging pointers
    const int srow = lane >> 3;
    const int sc   = lane & 7;
    const __bf16* k_src[2]; const __bf16* v_src[2];
    __bf16* k_dst[2]; __bf16* v_dst[2];
#pragma unroll
    for (int t = 0; t < 2; t++) {
        const int row = w * 16 + t * 8 + srow;
        const int c = sc ^ (row & 7);
        k_src[t] = kk + (size_t)row * DMODEL + h * HDIM + c * 8;
        v_src[t] = vT + (size_t)(h * HDIM + row) * S_LEN + c * 8;
        k_dst[t] = &Ks[(w * 16 + t * 8) * 64];
        v_dst[t] = &Vt[(w * 16 + t * 8) * 64];
    }

    f32x4 Ofrag[4];
#pragma unroll
    for (int nb = 0; nb < 4; nb++) Ofrag[nb] = (f32x4){0.f, 0.f, 0.f, 0.f};
    float m_r[4] = {-INFINITY, -INFINITY, -INFINITY, -INFINITY};
    float l_r[4] = {0.f, 0.f, 0.f, 0.f};

    __bf16* Pw = Ps + w * (16 * PITCH);

    for (int kt = 0; kt < S_LEN / 64; kt++) {
#pragma unroll
        for (int t = 0; t < 2; t++) {
            gld_lds16(k_dst[t], k_src[t]); k_src[t] += (size_t)64 * DMODEL;
            gld_lds16(v_dst[t], v_src[t]); v_src[t] += 64;
        }
        __syncthreads();

        // scores
        f32x4 sfrag[4];
#pragma unroll
        for (int nb = 0; nb < 4; nb++) {
            f32x4 acc = (f32x4){0.f, 0.f, 0.f, 0.f};
            const int n = nb * 16 + c0;
#pragma unroll
            for (int ks = 0; ks < 2; ks++) {
                const int cb = ks * 4 + quad;
                bf16x8 bfr = *(const bf16x8*)&Ks[n * 64 + ((cb ^ (n & 7)) << 3)];
                acc = __builtin_amdgcn_mfma_f32_16x16x32_bf16(qfrag[ks], bfr, acc, 0, 0, 0);
            }
            sfrag[nb] = acc;
        }

        // online softmax
        float alpha_v[4];
#pragma unroll
        for (int reg = 0; reg < 4; reg++) {
            float mloc = fmaxf(fmaxf(sfrag[0][reg], sfrag[1][reg]),
                               fmaxf(sfrag[2][reg], sfrag[3][reg]));
#pragma unroll
            for (int mask = 1; mask < 16; mask <<= 1)
                mloc = fmaxf(mloc, __shfl_xor(mloc, mask, 64));
            const float mnew = fmaxf(m_r[reg], mloc);
            const float al = __expf(m_r[reg] - mnew);
            m_r[reg] = mnew;
            float rsum = 0.f;
#pragma unroll
            for (int nb = 0; nb < 4; nb++) {
                float p = __expf(sfrag[nb][reg] - mnew);
                sfrag[nb][reg] = p;
                rsum += p;
            }
#pragma unroll
            for (int mask = 1; mask < 16; mask <<= 1)
                rsum += __shfl_xor(rsum, mask, 64);
            l_r[reg] = l_r[reg] * al + rsum;
            alpha_v[reg] = al;
        }

        // P: C-layout -> per-wave LDS strip -> A-layout
#pragma unroll
        for (int reg = 0; reg < 4; reg++) {
            const int prow = quad * 4 + reg;
#pragma unroll
            for (int nb = 0; nb < 4; nb++)
                Pw[prow * PITCH + nb * 16 + c0] = (__bf16)sfrag[nb][reg];
        }
        __asm__ __volatile__("s_waitcnt lgkmcnt(0)" ::: "memory");

        bf16x8 pfrag[2];
#pragma unroll
        for (int ks = 0; ks < 2; ks++)
            pfrag[ks] = *(const bf16x8*)&Pw[c0 * PITCH + ks * 32 + quad * 8];

        // O = O*alpha + P @ V
        const f32x4 av = {alpha_v[0], alpha_v[1], alpha_v[2], alpha_v[3]};
#pragma unroll
        for (int nb = 0; nb < 4; nb++) {
            f32x4 acc = Ofrag[nb] * av;
            const int n = nb * 16 + c0;
#pragma unroll
            for (int ks = 0; ks < 2; ks++) {
                const int cb = ks * 4 + quad;
                bf16x8 vf = *(const bf16x8*)&Vt[n * 64 + ((cb ^ (n & 7)) << 3)];
                acc = __builtin_amdgcn_mfma_f32_16x16x32_bf16(pfrag[ks], vf, acc, 0, 0, 0);
            }
            Ofrag[nb] = acc;
        }
        __syncthreads();
    }

    // epilogue: hi|lo|hi split into ctx2
#pragma unroll
    for (int reg = 0; reg < 4; reg++) {
        const float inv_l = 1.0f / l_r[reg];
        const int row = qb * 64 + w * 16 + quad * 4 + reg;
#pragma unroll
        for (int nb = 0; nb < 4; nb++) {
            const int col = h * HDIM + nb * 16 + c0;
            float val = Ofrag[nb][reg] * inv_l;
            __bf16 hi = (__bf16)val;
            __bf16 lo = (__bf16)(val - (float)hi);
            __bf16* p = ctx2 + (size_t)row * 3072 + col;
            p[0] = hi; p[1024] = lo; p[2048] = hi;
        }
    }
}

// ---------------------------------------------------------------------------
// fp32 -> bf16 transpose(+optional hi/hi/lo split along k): src [R,C] ->
// dst [C, dpitch] where dst[n][k] = src[k][n]; split writes hi@k, hi@R+k, lo@2R+k.
// Batched over blockIdx.z (src += z*sbatch, dst rows += z*nstride).
// ---------------------------------------------------------------------------
__global__ __launch_bounds__(256) void transpose_convert_kernel(
    const float* __restrict__ src, __bf16* __restrict__ dst,
    int R, int C, int dpitch, int split, long sbatch, int nstride)
{
    __shared__ float tile[32][33];
    src += (size_t)blockIdx.z * sbatch;
    const int r0 = blockIdx.y * 32, c0 = blockIdx.x * 32;
    const int tr = threadIdx.x >> 5, tc = threadIdx.x & 31;
#pragma unroll
    for (int i = 0; i < 4; i++)
        tile[tr + i * 8][tc] = src[(size_t)(r0 + tr + i * 8) * C + c0 + tc];
    __syncthreads();
    const int nbase = blockIdx.z * nstride + c0;
#pragma unroll
    for (int i = 0; i < 4; i++) {
        const int n = nbase + tr + i * 8;
        const int kk = r0 + tc;
        const float v = tile[tc][tr + i * 8];
        __bf16 hi = (__bf16)v;
        __bf16* dp = dst + (size_t)n * dpitch + kk;
        dp[0] = hi;
        if (split) { dp[R] = hi; dp[2 * R] = (__bf16)(v - (float)hi); }
    }
}

__global__ __launch_bounds__(256) void convert_bf16_kernel(
    const float* __restrict__ src, __bf16* __restrict__ dst, int n4)
{
    const int i = blockIdx.x * blockDim.x + threadIdx.x;
    if (i >= n4) return;
    float4 f = ((const float4*)src)[i];
    bf16x4 b;
    b[0] = (__bf16)f.x; b[1] = (__bf16)f.y; b[2] = (__bf16)f.z; b[3] = (__bf16)f.w;
    ((bf16x4*)dst)[i] = b;
}

// ---------------------------------------------------------------------------
// Launch
// ---------------------------------------------------------------------------
extern "C" void kernel_launch(void* const* d_in, const int* in_sizes, int n_in,
                              void* d_out, int out_size, void* d_ws, size_t ws_size,
                              hipStream_t stream) {
    const float* emb    = (const float*)d_in[0];
    const float* Wq     = (const float*)d_in[1];
    const float* Wdkv   = (const float*)d_in[2];
    const float* Wuk    = (const float*)d_in[3];
    const float* Wuv    = (const float*)d_in[4];
    const float* Wo     = (const float*)d_in[5];
    const float* wheelW = (const float*)d_in[6];
    const float* wheelB = (const float*)d_in[7];
    float* out = (float*)d_out;

    // workspace (bf16 elements). body2 aliases [emb|q|ckv|k] (dead by then).
    __bf16* ws = (__bf16*)d_ws;
    __bf16* emb_bf = ws;                         // 2,097,152
    __bf16* q_bf   = ws + 2097152;               // 2,097,152
    __bf16* ckv_bf = ws + 4194304;               //   524,288
    __bf16* k_bf   = ws + 4718592;               // 2,097,152
    __bf16* body2  = ws;                         // 6,291,456 (alias)
    __bf16* vT_bf  = ws + 6815744;               // 2,097,152
    __bf16* ctx2   = ws + 8912896;               // 6,291,456
    __bf16* Wqt    = ws + 15204352;              // 1,048,576
    __bf16* Wdkvt  = ws + 16252928;              //   262,144
    __bf16* Wukt   = ws + 16515072;              //   262,144
    __bf16* Wuvt   = ws + 16777216;              //   262,144
    __bf16* Wot2   = ws + 17039360;              // 3,145,728
    __bf16* Wct2   = ws + 20185088;              // 3,145,728

    // converts / transposes
    convert_bf16_kernel<<<2048, 256, 0, stream>>>(emb, emb_bf, (S_LEN * DMODEL) / 4);
    transpose_convert_kernel<<<dim3(32, 32, 1), 256, 0, stream>>>(Wq,   Wqt,   1024, 1024, 1024, 0, 0, 0);
    transpose_convert_kernel<<<dim3(8, 32, 1),  256, 0, stream>>>(Wdkv, Wdkvt, 1024, 256,  1024, 0, 0, 0);
    transpose_convert_kernel<<<dim3(32, 8, 1),  256, 0, stream>>>(Wuk,  Wukt,  256,  1024, 256,  0, 0, 0);
    transpose_convert_kernel<<<dim3(32, 8, 1),  256, 0, stream>>>(Wuv,  Wuvt,  256,  1024, 256,  0, 0, 0);
    transpose_convert_kernel<<<dim3(32, 32, 1), 256, 0, stream>>>(Wo,   Wot2,  1024, 1024, 3072, 1, 0, 0);
    transpose_convert_kernel<<<dim3(8, 32, 4),  256, 0, stream>>>(wheelW, Wct2, 1024, 256, 3072, 1, 1024 * 256, 256);

    // projections (q pre-scaled by 1/sqrt(64))
    gemm_bf16<<<dim3(8, 16), 256, 0, stream>>>(emb_bf, 1024, Wqt, 1024, S_LEN, 1024, 1024,
        nullptr, 0, nullptr, q_bf, 1024, 0, 0, 0.125f);
    gemm_bf16<<<dim3(2, 16), 256, 0, stream>>>(emb_bf, 1024, Wdkvt, 1024, S_LEN, 256, 1024,
        nullptr, 0, nullptr, ckv_bf, 256, 0, 0, 1.0f);
    gemm_bf16<<<dim3(8, 16), 256, 0, stream>>>(ckv_bf, 256, Wukt, 256, S_LEN, 1024, 256,
        nullptr, 0, nullptr, k_bf, 1024, 0, 0, 1.0f);
    gemm_bf16<<<dim3(8, 16), 256, 0, stream>>>(ckv_bf, 256, Wuvt, 256, S_LEN, 1024, 256,
        nullptr, 0, nullptr, vT_bf, 2048, 2, 0, 1.0f);   // transposed: vT[1024][2048]

    // attention -> ctx2 (hi|lo|hi)
    attn_mfma_kernel<<<dim3(S_LEN / 64, NHEADS), 256, 0, stream>>>(q_bf, k_bf, vT_bf, ctx2);

    // body = ctx @ Wo (split-exact): fp32 -> out[:,0:1024], bf16 split -> body2
    gemm_bf16<<<dim3(8, 16), 256, 0, stream>>>(ctx2, 3072, Wot2, 3072, S_LEN, 1024, 3072,
        out, 2048, nullptr, body2, 3072, 1, 1024, 1.0f);

    // wheels (all 4 as one GEMM) = body @ Wcat + b -> out[:,1024:2048]
    gemm_bf16<<<dim3(8, 16), 256, 0, stream>>>(body2, 3072, Wct2, 3072, S_LEN, 1024, 3072,
        out + 1024, 2048, wheelB, nullptr, 0, 0, 0, 1.0f);
}

// Round 4
// 273.194 us; speedup vs baseline: 6.9730x; 1.3280x over previous
//
#include <hip/hip_runtime.h>
#include <math.h>

#define S_LEN 2048
#define DMODEL 1024
#define NHEADS 16
#define HDIM 64
#define QPITCH 1280   // q|ckv merged activation pitch

typedef __bf16 bf16x8 __attribute__((ext_vector_type(8)));
typedef __bf16 bf16x4 __attribute__((ext_vector_type(4)));
typedef float  f32x4  __attribute__((ext_vector_type(4)));

// async global->LDS, 16B per lane. LDS dest = wave-uniform base + lane*16.
__device__ __forceinline__ void gld_lds16(void* lds, const void* g) {
    __builtin_amdgcn_global_load_lds(
        (__attribute__((address_space(1))) void*)(g),
        (__attribute__((address_space(3))) void*)(lds), 16, 0, 0);
}

// ---------------------------------------------------------------------------
// bf16 MFMA GEMM, double-buffered one-barrier pipeline.
// C[M,N] = A[M,K] @ Bt[N,K]^T. 128x128 tile, BK=64, 256 thr = 4 waves.
// grid.z = ksplit: each z-slice does K/gridDim.z, atomicAdd to Cf (Cb must be
// null in that case). Epilogue bf16 modes:
//   0: Cb[m][n] plain
//   3: B-split hi|hi|lo: p[0]=hi, p[soff]=hi, p[2soff]=lo
//   4: dual: n<1024 -> Cb[m][n]; n>=1024 -> Cb2[(n-1024)][m] (pitch ldcb2)
// ---------------------------------------------------------------------------
__global__ __launch_bounds__(256) void gemm_bf16(
    const __bf16* __restrict__ A, int lda,
    const __bf16* __restrict__ Bt, int ldb,
    int M, int N, int K,
    float* __restrict__ Cf, int ldcf, const float* __restrict__ bias,
    __bf16* __restrict__ Cb, int ldcb, int bmode, int soff,
    __bf16* __restrict__ Cb2, int ldcb2, float out_scale)
{
    __shared__ __bf16 sA[2][128 * 64];
    __shared__ __bf16 sB[2][128 * 64];

    const int tid  = threadIdx.x;
    const int lane = tid & 63;
    const int w    = tid >> 6;
    const int quad = lane >> 4;
    const int c0   = lane & 15;
    const int m0 = blockIdx.y * 128;
    const int n0 = blockIdx.x * 128;

    const int nkt_tot = K >> 6;
    const int nz  = gridDim.z;
    const int nkt = nkt_tot / nz;
    const int kt0 = blockIdx.z * nkt;

    // staging: thread loads 4 A-row-chunks + 4 B-row-chunks of 16B, swizzled
    const int srow = lane >> 3;
    const int sc   = lane & 7;
    const __bf16* a_src[4]; const __bf16* b_src[4];
    int dstoff[4];
#pragma unroll
    for (int t = 0; t < 4; t++) {
        const int row = w * 32 + t * 8 + srow;
        const int c = sc ^ (row & 7);
        a_src[t] = A  + (size_t)(m0 + row) * lda + kt0 * 64 + c * 8;
        b_src[t] = Bt + (size_t)(n0 + row) * ldb + kt0 * 64 + c * 8;
        dstoff[t] = (w * 32 + t * 8) * 64;
    }

    const int mw = (w & 1) * 64;
    const int nw = (w >> 1) * 64;
    int arow[4], brow[4];
#pragma unroll
    for (int i = 0; i < 4; i++) {
        arow[i] = mw + i * 16 + c0;
        brow[i] = nw + i * 16 + c0;
    }

    f32x4 acc[4][4];
#pragma unroll
    for (int i = 0; i < 4; i++)
#pragma unroll
        for (int j = 0; j < 4; j++) acc[i][j] = (f32x4){0.f, 0.f, 0.f, 0.f};

    // preload tile 0 into buffer 0
#pragma unroll
    for (int t = 0; t < 4; t++) {
        gld_lds16(&sA[0][dstoff[t]], a_src[t]); a_src[t] += 64;
        gld_lds16(&sB[0][dstoff[t]], b_src[t]); b_src[t] += 64;
    }

    for (int kt = 0; kt < nkt; kt++) {
        __syncthreads();                 // drains prefetch for 'cur' (issued one iter ago)
        const int cur = kt & 1;
        if (kt + 1 < nkt) {              // prefetch AFTER barrier -> overlaps compute
#pragma unroll
            for (int t = 0; t < 4; t++) {
                gld_lds16(&sA[cur ^ 1][dstoff[t]], a_src[t]); a_src[t] += 64;
                gld_lds16(&sB[cur ^ 1][dstoff[t]], b_src[t]); b_src[t] += 64;
            }
        }
#pragma unroll
        for (int ks = 0; ks < 2; ks++) {
            const int cb = ks * 4 + quad;
            bf16x8 af[4], bf[4];
#pragma unroll
            for (int i = 0; i < 4; i++)
                af[i] = *(const bf16x8*)&sA[cur][arow[i] * 64 + ((cb ^ (arow[i] & 7)) << 3)];
#pragma unroll
            for (int j = 0; j < 4; j++)
                bf[j] = *(const bf16x8*)&sB[cur][brow[j] * 64 + ((cb ^ (brow[j] & 7)) << 3)];
#pragma unroll
            for (int i = 0; i < 4; i++)
#pragma unroll
                for (int j = 0; j < 4; j++)
                    acc[i][j] = __builtin_amdgcn_mfma_f32_16x16x32_bf16(af[i], bf[j], acc[i][j], 0, 0, 0);
        }
    }

    // epilogue
    float bias_v[4];
    if (bias) {
#pragma unroll
        for (int j = 0; j < 4; j++) bias_v[j] = bias[n0 + nw + j * 16 + c0];
    }
#pragma unroll
    for (int i = 0; i < 4; i++) {
#pragma unroll
        for (int reg = 0; reg < 4; reg++) {
            const int m = m0 + mw + i * 16 + quad * 4 + reg;
#pragma unroll
            for (int j = 0; j < 4; j++) {
                const int n = n0 + nw + j * 16 + c0;
                float val = acc[i][j][reg] * out_scale;
                if (bias) val += bias_v[j];
                if (Cf) {
                    if (nz > 1) atomicAdd(&Cf[(size_t)m * ldcf + n], val);
                    else        Cf[(size_t)m * ldcf + n] = val;
                }
                if (Cb) {
                    if (bmode == 0) {
                        Cb[(size_t)m * ldcb + n] = (__bf16)val;
                    } else if (bmode == 3) {
                        __bf16 hi = (__bf16)val;
                        __bf16 lo = (__bf16)(val - (float)hi);
                        __bf16* p = Cb + (size_t)m * ldcb + n;
                        p[0] = hi; p[soff] = hi; p[2 * soff] = lo;
                    } else { // 4: dual k | vT
                        __bf16 hv = (__bf16)val;
                        if (n < 1024) Cb[(size_t)m * ldcb + n] = hv;
                        else          Cb2[(size_t)(n - 1024) * ldcb2 + m] = hv;
                    }
                }
            }
        }
    }
}

// ---------------------------------------------------------------------------
// MFMA flash attention, fixed-max softmax (shift-invariant; scores << M0
// overflow bound of ~100), double-buffered one-barrier staging.
// qs: bf16 [S, QPITCH] (q pre-scaled by 1/8, cols 0-1023); kk bf16 [S,1024];
// vT bf16 [1024, S]. Output ctx2 bf16 [S,3072] hi|lo|hi split.
// ---------------------------------------------------------------------------
#define PITCH 72
#define SOFT_M0 16.0f

__global__ __launch_bounds__(256) void attn_mfma_kernel(
    const __bf16* __restrict__ qs,
    const __bf16* __restrict__ kk,
    const __bf16* __restrict__ vT,
    __bf16* __restrict__ ctx2)
{
    __shared__ __bf16 Ks[2][64 * 64];
    __shared__ __bf16 Vt[2][64 * 64];
    __shared__ __bf16 Ps[4 * 16 * PITCH];

    const int h  = blockIdx.y;
    const int qb = blockIdx.x;
    const int tid  = threadIdx.x;
    const int lane = tid & 63;
    const int w    = tid >> 6;
    const int quad = lane >> 4;
    const int c0   = lane & 15;

    bf16x8 qfrag[2];
    {
        const __bf16* qrow = qs + (size_t)(qb * 64 + w * 16 + c0) * QPITCH + h * HDIM;
        qfrag[0] = *(const bf16x8*)(qrow + quad * 8);
        qfrag[1] = *(const bf16x8*)(qrow + 32 + quad * 8);
    }

    const int srow = lane >> 3;
    const int sc   = lane & 7;
    const __bf16* k_src[2]; const __bf16* v_src[2];
    int dstoff[2];
#pragma unroll
    for (int t = 0; t < 2; t++) {
        const int row = w * 16 + t * 8 + srow;
        const int c = sc ^ (row & 7);
        k_src[t] = kk + (size_t)row * DMODEL + h * HDIM + c * 8;
        v_src[t] = vT + (size_t)(h * HDIM + row) * S_LEN + c * 8;
        dstoff[t] = (w * 16 + t * 8) * 64;
    }

    f32x4 Ofrag[4];
#pragma unroll
    for (int nb = 0; nb < 4; nb++) Ofrag[nb] = (f32x4){0.f, 0.f, 0.f, 0.f};
    float l_r[4] = {0.f, 0.f, 0.f, 0.f};

    __bf16* Pw = Ps + w * (16 * PITCH);

    // preload tile 0
#pragma unroll
    for (int t = 0; t < 2; t++) {
        gld_lds16(&Ks[0][dstoff[t]], k_src[t]); k_src[t] += (size_t)64 * DMODEL;
        gld_lds16(&Vt[0][dstoff[t]], v_src[t]); v_src[t] += 64;
    }

    for (int kt = 0; kt < S_LEN / 64; kt++) {
        __syncthreads();
        const int cur = kt & 1;
        if (kt < S_LEN / 64 - 1) {
#pragma unroll
            for (int t = 0; t < 2; t++) {
                gld_lds16(&Ks[cur ^ 1][dstoff[t]], k_src[t]); k_src[t] += (size_t)64 * DMODEL;
                gld_lds16(&Vt[cur ^ 1][dstoff[t]], v_src[t]); v_src[t] += 64;
            }
        }

        // scores
        f32x4 sfrag[4];
#pragma unroll
        for (int nb = 0; nb < 4; nb++) {
            f32x4 acc = (f32x4){0.f, 0.f, 0.f, 0.f};
            const int n = nb * 16 + c0;
#pragma unroll
            for (int ks = 0; ks < 2; ks++) {
                const int cb = ks * 4 + quad;
                bf16x8 bfr = *(const bf16x8*)&Ks[cur][n * 64 + ((cb ^ (n & 7)) << 3)];
                acc = __builtin_amdgcn_mfma_f32_16x16x32_bf16(qfrag[ks], bfr, acc, 0, 0, 0);
            }
            sfrag[nb] = acc;
        }

        // P = exp(s - M0); accumulate per-lane partial row sums (no shuffles here)
#pragma unroll
        for (int reg = 0; reg < 4; reg++) {
            float p0 = __expf(sfrag[0][reg] - SOFT_M0);
            float p1 = __expf(sfrag[1][reg] - SOFT_M0);
            float p2 = __expf(sfrag[2][reg] - SOFT_M0);
            float p3 = __expf(sfrag[3][reg] - SOFT_M0);
            sfrag[0][reg] = p0; sfrag[1][reg] = p1;
            sfrag[2][reg] = p2; sfrag[3][reg] = p3;
            l_r[reg] += p0 + p1 + p2 + p3;
        }

        // P: C-layout -> per-wave LDS strip -> A-layout (wave-local, no barrier)
#pragma unroll
        for (int reg = 0; reg < 4; reg++) {
            const int prow = quad * 4 + reg;
#pragma unroll
            for (int nb = 0; nb < 4; nb++)
                Pw[prow * PITCH + nb * 16 + c0] = (__bf16)sfrag[nb][reg];
        }
        __asm__ __volatile__("s_waitcnt lgkmcnt(0)" ::: "memory");

        bf16x8 pfrag[2];
#pragma unroll
        for (int ks = 0; ks < 2; ks++)
            pfrag[ks] = *(const bf16x8*)&Pw[c0 * PITCH + ks * 32 + quad * 8];

        // O += P @ V (no alpha rescale with fixed max)
#pragma unroll
        for (int nb = 0; nb < 4; nb++) {
            f32x4 acc = Ofrag[nb];
            const int n = nb * 16 + c0;
#pragma unroll
            for (int ks = 0; ks < 2; ks++) {
                const int cb = ks * 4 + quad;
                bf16x8 vf = *(const bf16x8*)&Vt[cur][n * 64 + ((cb ^ (n & 7)) << 3)];
                acc = __builtin_amdgcn_mfma_f32_16x16x32_bf16(pfrag[ks], vf, acc, 0, 0, 0);
            }
            Ofrag[nb] = acc;
        }
    }

    // single final reduction of l over the 16 lanes holding each row
    float inv_l[4];
#pragma unroll
    for (int reg = 0; reg < 4; reg++) {
        float rsum = l_r[reg];
#pragma unroll
        for (int mask = 1; mask < 16; mask <<= 1)
            rsum += __shfl_xor(rsum, mask, 64);
        inv_l[reg] = 1.0f / rsum;
    }

    // epilogue: hi|lo|hi split into ctx2
#pragma unroll
    for (int reg = 0; reg < 4; reg++) {
        const int row = qb * 64 + w * 16 + quad * 4 + reg;
#pragma unroll
        for (int nb = 0; nb < 4; nb++) {
            const int col = h * HDIM + nb * 16 + c0;
            float val = Ofrag[nb][reg] * inv_l[reg];
            __bf16 hi = (__bf16)val;
            __bf16 lo = (__bf16)(val - (float)hi);
            __bf16* p = ctx2 + (size_t)row * 3072 + col;
            p[0] = hi; p[1024] = lo; p[2048] = hi;
        }
    }
}

// ---------------------------------------------------------------------------
// fp32 -> bf16 transpose: src [R,C] -> dst[n][k] = src[k][n]*scale.
// split 0: hi only. 1: B-split (hi, hi@R, lo@2R). 2: A-split (hi, lo@R, hi@2R).
// Batched over blockIdx.z.
// ---------------------------------------------------------------------------
__global__ __launch_bounds__(256) void transpose_convert_kernel(
    const float* __restrict__ src, __bf16* __restrict__ dst,
    int R, int C, int dpitch, int split, long sbatch, int nstride, float scale)
{
    __shared__ float tile[32][33];
    src += (size_t)blockIdx.z * sbatch;
    const int r0 = blockIdx.y * 32, c0 = blockIdx.x * 32;
    const int tr = threadIdx.x >> 5, tc = threadIdx.x & 31;
#pragma unroll
    for (int i = 0; i < 4; i++)
        tile[tr + i * 8][tc] = src[(size_t)(r0 + tr + i * 8) * C + c0 + tc];
    __syncthreads();
    const int nbase = blockIdx.z * nstride + c0;
#pragma unroll
    for (int i = 0; i < 4; i++) {
        const int n = nbase + tr + i * 8;
        const int kk = r0 + tc;
        const float v = tile[tc][tr + i * 8] * scale;
        __bf16 hi = (__bf16)v;
        __bf16* dp = dst + (size_t)n * dpitch + kk;
        dp[0] = hi;
        if (split == 1)      { dp[R] = hi; dp[2 * R] = (__bf16)(v - (float)hi); }
        else if (split == 2) { dp[R] = (__bf16)(v - (float)hi); dp[2 * R] = hi; }
    }
}

// fp32 row-major [rows][1024] -> bf16 [rows][3072] B-split (hi|hi|lo)
__global__ __launch_bounds__(256) void convert_bsplit_kernel(
    const float* __restrict__ src, __bf16* __restrict__ dst, int n4)
{
    const int i = blockIdx.x * blockDim.x + threadIdx.x;
    if (i >= n4) return;
    const int row = i >> 8;
    const int c4  = (i & 255) * 4;
    float4 f = ((const float4*)src)[i];
    __bf16* p = dst + (size_t)row * 3072 + c4;
    float fa[4] = {f.x, f.y, f.z, f.w};
#pragma unroll
    for (int e = 0; e < 4; e++) {
        __bf16 hi = (__bf16)fa[e];
        p[e] = hi; p[1024 + e] = hi; p[2048 + e] = (__bf16)(fa[e] - (float)hi);
    }
}

__global__ __launch_bounds__(256) void convert_bf16_kernel(
    const float* __restrict__ src, __bf16* __restrict__ dst, int n4)
{
    const int i = blockIdx.x * blockDim.x + threadIdx.x;
    if (i >= n4) return;
    float4 f = ((const float4*)src)[i];
    bf16x4 b;
    b[0] = (__bf16)f.x; b[1] = (__bf16)f.y; b[2] = (__bf16)f.z; b[3] = (__bf16)f.w;
    ((bf16x4*)dst)[i] = b;
}

__global__ __launch_bounds__(256) void zero_f32_kernel(float* __restrict__ p, int n4)
{
    const int i = blockIdx.x * blockDim.x + threadIdx.x;
    if (i < n4) ((float4*)p)[i] = make_float4(0.f, 0.f, 0.f, 0.f);
}

// bias[0:1024]=0, bias[1024:2048]=wheelB flat
__global__ __launch_bounds__(256) void build_bias_kernel(
    const float* __restrict__ wb, float* __restrict__ bias)
{
    const int i = blockIdx.x * blockDim.x + threadIdx.x;
    bias[i] = (i < 1024) ? 0.f : wb[i - 1024];
}

// ---------------------------------------------------------------------------
// Launch
// ---------------------------------------------------------------------------
extern "C" void kernel_launch(void* const* d_in, const int* in_sizes, int n_in,
                              void* d_out, int out_size, void* d_ws, size_t ws_size,
                              hipStream_t stream) {
    const float* emb    = (const float*)d_in[0];
    const float* Wq     = (const float*)d_in[1];
    const float* Wdkv   = (const float*)d_in[2];
    const float* Wuk    = (const float*)d_in[3];
    const float* Wuv    = (const float*)d_in[4];
    const float* Wo     = (const float*)d_in[5];
    const float* wheelW = (const float*)d_in[6];
    const float* wheelB = (const float*)d_in[7];
    float* out = (float*)d_out;

    // workspace layout (bf16 element offsets); high-water 42.5 MB
    __bf16* ws = (__bf16*)d_ws;
    __bf16* Bt_full = ws;                        // [2048][3072]      6,291,456
    __bf16* Wqc_t   = ws + 6291456;              // [1280][1024]      1,310,720
    __bf16* Wukv_t  = ws + 7602176;              // [2048][256]         524,288
    float*  biasbuf = (float*)(ws + 8126464);    // fp32[2048]            4,096
    // E region (6,291,456): WcT2a+Wo_rm, then emb_bf, then ctx2
    __bf16* WcT2a   = ws + 8130560;              // [1024][3072] A-split
    __bf16* Wo_rm   = ws + 11276288;             // [1024][3072] B-split
    __bf16* emb_bf  = ws + 8130560;              // [2048][1024] (after Wf GEMM)
    __bf16* ctx2    = ws + 8130560;              // [2048][3072] (attn out)
    float*  Wf_acc  = (float*)(ws + 14422016);   // fp32[1024][1024] (aliases qc_bf)
    __bf16* qc_bf   = ws + 14422016;             // [2048][1280]
    __bf16* k_bf    = ws + 17043456;             // [2048][1024]
    __bf16* vT_bf   = ws + 19140608;             // [1024][2048]

    // ---- weight prep ----
    transpose_convert_kernel<<<dim3(32, 32, 1), 256, 0, stream>>>(Wq,   Wqc_t,            1024, 1024, 1024, 0, 0, 0, 0.125f);
    transpose_convert_kernel<<<dim3(8, 32, 1),  256, 0, stream>>>(Wdkv, Wqc_t + 1048576,  1024, 256,  1024, 0, 0, 0, 1.0f);
    transpose_convert_kernel<<<dim3(32, 8, 1),  256, 0, stream>>>(Wuk,  Wukv_t,           256,  1024, 256,  0, 0, 0, 1.0f);
    transpose_convert_kernel<<<dim3(32, 8, 1),  256, 0, stream>>>(Wuv,  Wukv_t + 262144,  256,  1024, 256,  0, 0, 0, 1.0f);
    transpose_convert_kernel<<<dim3(32, 32, 1), 256, 0, stream>>>(Wo,   Bt_full,          1024, 1024, 3072, 1, 0, 0, 1.0f);
    transpose_convert_kernel<<<dim3(8, 32, 4),  256, 0, stream>>>(wheelW, WcT2a,          1024, 256,  3072, 2, 1024 * 256, 256, 1.0f);
    convert_bsplit_kernel<<<1024, 256, 0, stream>>>(Wo, Wo_rm, 262144);

    // ---- Wf = Wo @ Wc (fp32-exact via split operands), split-K x4 ----
    zero_f32_kernel<<<1024, 256, 0, stream>>>(Wf_acc, 262144);
    gemm_bf16<<<dim3(8, 8, 4), 256, 0, stream>>>(WcT2a, 3072, Wo_rm, 3072, 1024, 1024, 3072,
        Wf_acc, 1024, nullptr, nullptr, 0, 0, 0, nullptr, 0, 1.0f);
    convert_bsplit_kernel<<<1024, 256, 0, stream>>>(Wf_acc, Bt_full + (size_t)1024 * 3072, 262144);
    build_bias_kernel<<<8, 256, 0, stream>>>(wheelB, biasbuf);

    // ---- activations ----
    convert_bf16_kernel<<<2048, 256, 0, stream>>>(emb, emb_bf, (S_LEN * DMODEL) / 4);

    // q|ckv merged: [2048,1280] (q pre-scaled via Wq weights)
    gemm_bf16<<<dim3(10, 16, 1), 256, 0, stream>>>(emb_bf, 1024, Wqc_t, 1024, S_LEN, 1280, 1024,
        nullptr, 0, nullptr, qc_bf, 1280, 0, 0, nullptr, 0, 1.0f);

    // k|vT merged: A = ckv (cols 1024.. of qc_bf)
    gemm_bf16<<<dim3(16, 16, 1), 256, 0, stream>>>(qc_bf + 1024, 1280, Wukv_t, 256, S_LEN, 2048, 256,
        nullptr, 0, nullptr, k_bf, 1024, 4, 0, vT_bf, 2048, 1.0f);

    // attention -> ctx2 (hi|lo|hi)
    attn_mfma_kernel<<<dim3(S_LEN / 64, NHEADS), 256, 0, stream>>>(qc_bf, k_bf, vT_bf, ctx2);

    // final fused GEMM: out[:,0:1024]=ctx@Wo, out[:,1024:2048]=ctx@Wf + b
    gemm_bf16<<<dim3(16, 16, 1), 256, 0, stream>>>(ctx2, 3072, Bt_full, 3072, S_LEN, 2048, 3072,
        out, 2048, biasbuf, nullptr, 0, 0, 0, nullptr, 0, 1.0f);
}